// Round 4
// baseline (163.768 us; speedup 1.0000x reference)
//
#include <hip/hip_runtime.h>
#include <hip/hip_bf16.h>

// ---- types ----
typedef __bf16 bf16_t;
typedef __bf16 bf16x8 __attribute__((ext_vector_type(8)));
typedef __bf16 bf16x4 __attribute__((ext_vector_type(4)));
typedef float  f32x4  __attribute__((ext_vector_type(4)));

#define NROWS 8192
#define INDIM 256
#define HID   256
#define NCAT  512

// async global->LDS, 16B per lane (dest = wave-uniform base + lane*16)
__device__ __forceinline__ void gload16(const bf16_t* g, bf16_t* l) {
    __builtin_amdgcn_global_load_lds(
        (const __attribute__((address_space(1))) void*)g,
        (__attribute__((address_space(3))) void*)l,
        16, 0, 0);
}

// raw barrier (no implicit cnt drain)
__device__ __forceinline__ void bar() {
    asm volatile("" ::: "memory");
    __builtin_amdgcn_s_barrier();
    asm volatile("" ::: "memory");
}

#define VMCNT0 asm volatile("s_waitcnt vmcnt(0)" ::: "memory")
#define LGKM0  asm volatile("s_waitcnt lgkmcnt(0)" ::: "memory")

// ============ kernel 1: row sums (read-only) + weight transposes ============
__global__ __launch_bounds__(256) void k_rowsum(const float* __restrict__ adj,
                                                float* __restrict__ d_inv,
                                                const float* __restrict__ Wf,
                                                const float* __restrict__ Ws,
                                                bf16_t* __restrict__ Wtf,
                                                bf16_t* __restrict__ Wts) {
    const int b = blockIdx.x;
    if (b >= NROWS / 4) {
        const int i = (b - NROWS / 4) * 256 + threadIdx.x;
        const int n = i >> 8, k = i & 255;
        Wtf[i] = (bf16_t)Wf[k * 256 + n];
        Wts[i] = (bf16_t)Ws[k * 256 + n];
        return;
    }
    const int lane = threadIdx.x & 63;
    const int wid  = threadIdx.x >> 6;
    const int row  = b * 4 + wid;
    const float4* rp = (const float4*)(adj + (size_t)row * NROWS);
    float s = 0.f;
#pragma unroll 8
    for (int i = lane; i < NROWS / 4; i += 64) {
        float4 v = rp[i];
        s += (v.x + v.y) + (v.z + v.w);
    }
#pragma unroll
    for (int off = 32; off; off >>= 1) s += __shfl_down(s, off);
    if (lane == 0) d_inv[row] = 1.0f / sqrtf(s + 1e-9f);
}

// ===================== kernel 2: Yt[c][j] = bf16(d_j * X[j][c]) ==============
__global__ __launch_bounds__(256) void k_prep_x(const float* __restrict__ fx,
                                                const float* __restrict__ sx,
                                                const float* __restrict__ d_inv,
                                                bf16_t* __restrict__ Yt) {
    __shared__ bf16_t T[64][72];
    const int tid = threadIdx.x;
    const int j0 = blockIdx.x * 64;
    const int c0 = blockIdx.y * 64;
    const float* src = (c0 < 256) ? fx : sx;
    const int cc0 = (c0 < 256) ? c0 : (c0 - 256);
#pragma unroll
    for (int i = 0; i < 4; ++i) {
        int s = tid + i * 256;
        int jr = s >> 4, c4 = (s & 15) * 4;
        float dj = d_inv[j0 + jr];
        float4 v = *(const float4*)(src + (size_t)(j0 + jr) * 256 + cc0 + c4);
        bf16x4 o;
        o[0] = (bf16_t)(v.x * dj); o[1] = (bf16_t)(v.y * dj);
        o[2] = (bf16_t)(v.z * dj); o[3] = (bf16_t)(v.w * dj);
        *(bf16x4*)(&T[jr][c4]) = o;
    }
    __syncthreads();
#pragma unroll
    for (int i = 0; i < 4; ++i) {
        int s = tid + i * 256;
        int cr = s >> 4, j4 = (s & 15) * 4;
        bf16x4 o;
        o[0] = T[j4 + 0][cr]; o[1] = T[j4 + 1][cr];
        o[2] = T[j4 + 2][cr]; o[3] = T[j4 + 3][cr];
        *(bf16x4*)(Yt + (size_t)(c0 + cr) * NROWS + j0 + j4) = o;
    }
}

// ========= kernel 3: 256x256 GEMM, 2-phase/tile, cross-barrier prereads =====
// Same schedule as round 3, with the prologue race FIXED: the tile-0 preread
// reads rows written by OTHER waves' ds_writes, so it must sit between two
// barriers (writes -> LGKM0 -> bar -> preread -> LGKM0 -> bar -> loop).
// Round 3 had only the trailing barrier -> wave 0 preread rows 8..63 before
// waves 1..7 wrote them -> tile 0 corrupt -> absmax 6.8e-2.
// In-loop prereads are safe: every slot read is >=2 barriers after its
// cross-wave write/DMA, and each a_write_half's implicit counted vmcnt
// FIFO-drains all older B DMAs, with a barrier between drain and read.

__device__ __forceinline__ void stage_b(bf16_t* dst, const bf16_t* gsrc,
                                        int tid) {
#pragma unroll
    for (int c = 0; c < 2; ++c) {
        int r    = c * 64 + (tid >> 3);
        int gcol = ((tid & 7) * 8) ^ ((r & 7) * 8);   // involution
        gload16(gsrc + (size_t)r * NROWS + gcol, dst + c * 4096 + tid * 8);
    }
}

// fp32 A half-tile (128 rows x 64 cols): 2 rows/thread, 8 f32 each -> 4 f32x4
__device__ __forceinline__ void a_load_half(const float* Ag, int h, size_t k2,
                                            int tid, f32x4 R[4]) {
#pragma unroll
    for (int c = 0; c < 2; ++c) {
        const float* p = Ag + (size_t)(h * 128 + c * 64 + (tid >> 3)) * NROWS
                            + k2 + (tid & 7) * 8;
        R[c * 2 + 0] = *(const f32x4*)(p);
        R[c * 2 + 1] = *(const f32x4*)(p + 4);
    }
}

// cvt + write with the SAME XOR swizzle the read path uses (write-side)
__device__ __forceinline__ void a_write_half(bf16_t* dst, const f32x4 R[4],
                                             int tid) {
#pragma unroll
    for (int c = 0; c < 2; ++c) {
        int r   = c * 64 + (tid >> 3);
        int col = ((tid & 7) * 8) ^ ((r & 7) * 8);
        f32x4 v0 = R[c * 2], v1 = R[c * 2 + 1];
        bf16x8 o;
        o[0] = (bf16_t)v0[0]; o[1] = (bf16_t)v0[1];
        o[2] = (bf16_t)v0[2]; o[3] = (bf16_t)v0[3];
        o[4] = (bf16_t)v1[0]; o[5] = (bf16_t)v1[1];
        o[6] = (bf16_t)v1[2]; o[7] = (bf16_t)v1[3];
        *(bf16x8*)(dst + r * 64 + col) = o;
    }
}

__device__ __forceinline__ void frag_a(const bf16_t* base, bf16x8 af[4][2],
                                       int arow, int c0, int c1) {
#pragma unroll
    for (int mi = 0; mi < 4; ++mi) {
        af[mi][0] = *(const bf16x8*)(base + (arow + mi * 16) * 64 + c0);
        af[mi][1] = *(const bf16x8*)(base + (arow + mi * 16) * 64 + c1);
    }
}

__device__ __forceinline__ void frag_b(const bf16_t* base, bf16x8 bf2[2][2],
                                       int brow, int c0, int c1) {
#pragma unroll
    for (int ni = 0; ni < 2; ++ni) {
        bf2[ni][0] = *(const bf16x8*)(base + (brow + ni * 16) * 64 + c0);
        bf2[ni][1] = *(const bf16x8*)(base + (brow + ni * 16) * 64 + c1);
    }
}

template <int Q>
__device__ __forceinline__ void mfma_q(f32x4 acc[4][4][2],
                                       const bf16x8 af[4][2],
                                       const bf16x8 bf2[2][2]) {
    __builtin_amdgcn_s_setprio(1);
#pragma unroll
    for (int ks = 0; ks < 2; ++ks)
#pragma unroll
        for (int mi = 0; mi < 4; ++mi)
#pragma unroll
            for (int ni = 0; ni < 2; ++ni)
                acc[Q][mi][ni] = __builtin_amdgcn_mfma_f32_16x16x32_bf16(
                    af[mi][ks], bf2[ni][ks], acc[Q][mi][ni], 0, 0, 0);
    __builtin_amdgcn_s_setprio(0);
}

__global__ __launch_bounds__(512, 2) void k_gemm8(const float* __restrict__ adj,
                                                  const bf16_t* __restrict__ Yt,
                                                  bf16_t* __restrict__ msgp,
                                                  int KCH) {
    __shared__ bf16_t SH[8 * 8192];              // 128 KB contiguous
    bf16_t* As = SH;                             // A half-slots 0..3
    bf16_t* Bs = SH + 4 * 8192;                  // B half-slots 0..3
    const int tid  = threadIdx.x;
    const int lane = tid & 63;
    const int w    = tid >> 6;
    const int wrow = w >> 2, wcol = w & 3;       // 2M x 4N waves
    const int lr = lane & 15, hi = lane >> 4;

    // z-per-XCD decode (round-robin dispatch assumption; perf heuristic only)
    const int bid = blockIdx.x;
    const int c  = bid & 7;                      // XCD
    const int j  = bid >> 3;                     // 0..31 within XCD
    const int z  = c >> 1;                       // K-chunk pinned to XCD pair
    const int y  = (c & 1) * 16 + (j >> 1);
    const int x  = j & 1;
    const int m0 = y * 256, n0 = x * 256;
    const size_t kbase = (size_t)z * KCH;

    const float*  Ag = adj + (size_t)m0 * NROWS + kbase;
    const bf16_t* Bg = Yt + (size_t)n0 * NROWS + kbase;

    const int sw = (lr & 7) * 8;                 // read-side swizzle
    const int c0 = (hi * 8) ^ sw;
    const int c1 = c0 ^ 32;
    const int arow = wrow * 64 + lr;
    const int brow = wcol * 32 + lr;

    f32x4 acc[4][4][2] = {};
    const int NT = KCH / 64;                     // tiles (even)

    // steady-state register state, live across tiles
    f32x4 R[4];                                  // A staging buffer (16 VGPR)
    bf16x8 af[4][2], bA[2][2], bB[2][2];         // MFMA fragments (64 VGPR)

    // prologue: B tiles 0,1 via DMA; A tiles 0,1 via reg-cvt; preread tile 0
    {
        f32x4 T[4];
        stage_b(Bs + 0 * 8192, Bg, tid);
        stage_b(Bs + 1 * 8192, Bg + (size_t)128 * NROWS, tid);
        stage_b(Bs + 2 * 8192, Bg + 64, tid);
        stage_b(Bs + 3 * 8192, Bg + (size_t)128 * NROWS + 64, tid);
        a_load_half(Ag, 0, 0, tid, R);
        a_load_half(Ag, 1, 0, tid, T);
        a_write_half(As + 0 * 8192, R, tid);
        a_write_half(As + 1 * 8192, T, tid);
        a_load_half(Ag, 0, 64, tid, R);
        a_load_half(Ag, 1, 64, tid, T);
        a_write_half(As + 2 * 8192, R, tid);     // cvt waits k=64 loads ->
        a_write_half(As + 3 * 8192, T, tid);     //   all 4 B DMAs (older) done
        a_load_half(Ag, 0, 128, tid, R);         // R <- (t2,h0), in flight
        LGKM0;                                   // own ds_writes published
    }
    bar();                                       // ALL waves' writes visible
    // preread tile 0 fragments (cross-wave data now valid)
    frag_a(As + 0 * 8192, af, arow, c0, c1);
    frag_b(Bs + 0 * 8192, bA, brow, c0, c1);
    frag_b(Bs + 1 * 8192, bB, brow, c0, c1);
    LGKM0;                                       // prereads complete
    bar();                                       // before PhA overwrites

    // per-tile body: 2 phases. PhA: Q00,Q01 (row-block 0). PhB: Q11,Q10.
#define TBODY(PP, tt)                                                         \
    {                                                                         \
        bf16_t* Ah0 = As + ((PP) * 2 + 0) * 8192;                             \
        bf16_t* Ah1 = As + ((PP) * 2 + 1) * 8192;                             \
        bf16_t* Bh0 = Bs + ((PP) * 2 + 0) * 8192;                             \
        bf16_t* Bh1 = Bs + ((PP) * 2 + 1) * 8192;                             \
        bf16_t* An0 = As + (((PP) ^ 1) * 2 + 0) * 8192;                       \
        bf16_t* Bn0 = Bs + (((PP) ^ 1) * 2 + 0) * 8192;                       \
        bf16_t* Bn1 = Bs + (((PP) ^ 1) * 2 + 1) * 8192;                       \
        const bool full  = ((tt) <= NT - 3);                                  \
        const bool fnext = ((tt) <= NT - 4);                                  \
        const size_t k2 = (size_t)((tt) + 2) * 64;                            \
        const size_t k3 = (size_t)((tt) + 3) * 64;                            \
        /* PhA: stage Bh0<-t+2; Ah0<-R (vmcnt(2): B DMAs stay in flight); */  \
        /*      R <- (t+2,h1).  MFMA Q00,Q01 on preread af,bA,bB.         */  \
        if (full) {                                                           \
            stage_b(Bh0, Bg + k2, tid);                                       \
            a_write_half(Ah0, R, tid);                                        \
            a_load_half(Ag, 1, k2, tid, R);                                   \
        }                                                                     \
        mfma_q<0>(acc, af, bA);                                               \
        mfma_q<1>(acc, af, bB);                                               \
        frag_a(Ah1, af, arow, c0, c1);      /* preread for PhB (WAR ok) */    \
        LGKM0;                              /* reads done + writes published*/\
        bar();                                                                \
        /* PhB: stage Bh1<-t+2; Ah1<-R; R <- (t+3,h0).  MFMA Q11,Q10. */      \
        if (full) {                                                           \
            stage_b(Bh1, Bg + (size_t)128 * NROWS + k2, tid);                 \
            a_write_half(Ah1, R, tid);                                        \
        }                                                                     \
        if (fnext) a_load_half(Ag, 0, k3, tid, R);                            \
        if ((tt) == NT - 2) VMCNT0;         /* drain before final prereads */ \
        mfma_q<3>(acc, af, bB);                                               \
        mfma_q<2>(acc, af, bA);                                               \
        if ((tt) != NT - 1) {               /* preread next tile (other PP) */\
            frag_a(An0, af, arow, c0, c1);                                    \
            frag_b(Bn0, bA, brow, c0, c1);                                    \
            frag_b(Bn1, bB, brow, c0, c1);                                    \
        }                                                                     \
        LGKM0;                                                                \
        bar();                                                                \
    }

    for (int t = 0; t < NT; t += 2) {
        TBODY(0, t);
        TBODY(1, t + 1);
    }
#undef TBODY

    // epilogue: LDS-transpose each 128x128 quadrant, store bf16 coalesced
    bf16_t* mpb = msgp + (size_t)z * NROWS * NCAT;
    float* ep = (float*)SH;                      // 128 x (stride 133) fp32
    const int erow = tid >> 2, ecb = (tid & 3) * 32;
#pragma unroll
    for (int q4 = 0; q4 < 4; ++q4) {
        const int qm = q4 >> 1, qn = q4 & 1;
        bar();
#pragma unroll
        for (int mi = 0; mi < 4; ++mi)
#pragma unroll
            for (int ni = 0; ni < 2; ++ni)
#pragma unroll
                for (int r = 0; r < 4; ++r)
                    ep[(wrow * 64 + mi * 16 + hi * 4 + r) * 133
                       + wcol * 32 + ni * 16 + lr] = acc[q4][mi][ni][r];
        LGKM0;
        bar();
        bf16_t* gp = mpb + (size_t)(m0 + qm * 128 + erow) * NCAT
                         + n0 + qn * 128 + ecb;
#pragma unroll
        for (int j2 = 0; j2 < 4; ++j2) {
            f32x4 v0 = *(const f32x4*)(ep + erow * 133 + ecb + j2 * 8);
            f32x4 v1 = *(const f32x4*)(ep + erow * 133 + ecb + j2 * 8 + 4);
            bf16x8 o;
            o[0] = (bf16_t)v0[0]; o[1] = (bf16_t)v0[1];
            o[2] = (bf16_t)v0[2]; o[3] = (bf16_t)v0[3];
            o[4] = (bf16_t)v1[0]; o[5] = (bf16_t)v1[1];
            o[6] = (bf16_t)v1[2]; o[7] = (bf16_t)v1[3];
            *(bf16x8*)(gp + j2 * 8) = o;
        }
    }
}

// ===================== kernel 4: H_f/H_s + attention + blend =================
template <int NP>
__global__ __launch_bounds__(256) void k_fuse(const bf16_t* __restrict__ msg,
                                              const float* __restrict__ d_inv,
                                              const bf16_t* __restrict__ Wtf,
                                              const bf16_t* __restrict__ Wts,
                                              const float* __restrict__ bfv,
                                              const float* __restrict__ bsv,
                                              const float* __restrict__ Watt,
                                              const float* __restrict__ batt,
                                              float* __restrict__ out) {
    __shared__ bf16_t Ms[32][520];
    __shared__ float attnbuf[4][32];
    const int tid = threadIdx.x, lane = tid & 63, w = tid >> 6;
    const int r0 = blockIdx.x * 32;
    const int lr = lane & 15, lk = (lane >> 4) * 8;

#pragma unroll
    for (int i = 0; i < 8; ++i) {
        int s = tid + i * 256;              // 0..2047
        int r = s >> 6, c8 = (s & 63) * 8;
        float di = d_inv[r0 + r];
        size_t off = (size_t)(r0 + r) * NCAT + c8;
        float a8[8] = {};
#pragma unroll
        for (int p = 0; p < NP; ++p) {
            bf16x8 v = *(const bf16x8*)(msg + (size_t)p * NROWS * NCAT + off);
#pragma unroll
            for (int j = 0; j < 8; ++j) a8[j] += (float)v[j];
        }
        bf16x8 o;
#pragma unroll
        for (int j = 0; j < 8; ++j) o[j] = (bf16_t)(a8[j] * di);
        *(bf16x8*)(&Ms[r][c8]) = o;
    }
    __syncthreads();

    f32x4 accf[2][4] = {}, accs[2][4] = {};
#pragma unroll
    for (int ks = 0; ks < 8; ++ks) {
        bf16x8 af[2], as2[2];
#pragma unroll
        for (int mi = 0; mi < 2; ++mi) {
            af[mi]  = *(const bf16x8*)(&Ms[mi * 16 + lr][ks * 32 + lk]);
            as2[mi] = *(const bf16x8*)(&Ms[mi * 16 + lr][256 + ks * 32 + lk]);
        }
#pragma unroll
        for (int ni = 0; ni < 4; ++ni) {
            int col = w * 64 + ni * 16 + lr;
            bf16x8 bwf = *(const bf16x8*)(Wtf + col * 256 + ks * 32 + lk);
            bf16x8 bws = *(const bf16x8*)(Wts + col * 256 + ks * 32 + lk);
#pragma unroll
            for (int mi = 0; mi < 2; ++mi) {
                accf[mi][ni] = __builtin_amdgcn_mfma_f32_16x16x32_bf16(
                    af[mi], bwf, accf[mi][ni], 0, 0, 0);
                accs[mi][ni] = __builtin_amdgcn_mfma_f32_16x16x32_bf16(
                    as2[mi], bws, accs[mi][ni], 0, 0, 0);
            }
        }
    }

    float par[2][4] = {};
#pragma unroll
    for (int ni = 0; ni < 4; ++ni) {
        int col = w * 64 + ni * 16 + lr;
        float bf_ = bfv[col], bs_ = bsv[col];
        float wf = Watt[col], ws_ = Watt[256 + col];
#pragma unroll
        for (int mi = 0; mi < 2; ++mi)
#pragma unroll
            for (int r = 0; r < 4; ++r) {
                float f = accf[mi][ni][r] + bf_; f = f > 0.f ? f : 0.f;
                float s = accs[mi][ni][r] + bs_; s = s > 0.f ? s : 0.f;
                accf[mi][ni][r] = f; accs[mi][ni][r] = s;
                par[mi][r] += f * wf + s * ws_;
            }
    }
#pragma unroll
    for (int off = 1; off < 16; off <<= 1)
#pragma unroll
        for (int mi = 0; mi < 2; ++mi)
#pragma unroll
            for (int r = 0; r < 4; ++r)
                par[mi][r] += __shfl_xor(par[mi][r], off);
    if (lr == 0) {
#pragma unroll
        for (int mi = 0; mi < 2; ++mi)
#pragma unroll
            for (int r = 0; r < 4; ++r)
                attnbuf[w][mi * 16 + (lane >> 4) * 4 + r] = par[mi][r];
    }
    __syncthreads();

    const float ba = batt[0];
#pragma unroll
    for (int mi = 0; mi < 2; ++mi)
#pragma unroll
        for (int r = 0; r < 4; ++r) {
            int rr = mi * 16 + (lane >> 4) * 4 + r;
            float tot = attnbuf[0][rr] + attnbuf[1][rr] + attnbuf[2][rr] +
                        attnbuf[3][rr] + ba;
            float attn = 1.0f / (1.0f + expf(-tot));
#pragma unroll
            for (int ni = 0; ni < 4; ++ni) {
                int col = w * 64 + ni * 16 + lr;
                out[(size_t)(r0 + rr) * 256 + col] =
                    attn * accf[mi][ni][r] + (1.0f - attn) * accs[mi][ni][r];
            }
        }
}

// ===================== launch =====================
extern "C" void kernel_launch(void* const* d_in, const int* in_sizes, int n_in,
                              void* d_out, int out_size, void* d_ws, size_t ws_size,
                              hipStream_t stream) {
    (void)in_sizes; (void)n_in; (void)out_size; (void)ws_size;
    const float* fx   = (const float*)d_in[0];
    const float* sx   = (const float*)d_in[1];
    const float* adj  = (const float*)d_in[2];
    const float* Wf   = (const float*)d_in[3];
    const float* bfv  = (const float*)d_in[4];
    const float* Ws   = (const float*)d_in[5];
    const float* bsv  = (const float*)d_in[6];
    const float* Watt = (const float*)d_in[7];
    const float* batt = (const float*)d_in[8];
    float* out = (float*)d_out;

    char* ws = (char*)d_ws;
    float*  d_inv = (float*)(ws);                      // 32 KB
    bf16_t* Yt    = (bf16_t*)(ws + 32768);             // 8 MB   [512][8192]
    bf16_t* Wtf   = (bf16_t*)(ws + 8421376);           // 128 KB
    bf16_t* Wts   = (bf16_t*)(ws + 8552448);           // 128 KB
    bf16_t* msgp  = (bf16_t*)(ws + 8683520);           // 4 x 8 MB bf16 partials

    const int SK = 4;                                  // KCH = 2048
    k_rowsum<<<NROWS / 4 + 256, 256, 0, stream>>>(adj, d_inv, Wf, Ws, Wtf, Wts);
    k_prep_x<<<dim3(NROWS / 64, NCAT / 64), 256, 0, stream>>>(fx, sx, d_inv, Yt);
    k_gemm8<<<64 * SK, 512, 0, stream>>>(adj, Yt, msgp, NROWS / SK);
    k_fuse<4><<<NROWS / 32, 256, 0, stream>>>(msgp, d_inv, Wtf, Wts, bfv,
                                              bsv, Watt, batt, out);
}

// Round 5
// 154.129 us; speedup vs baseline: 1.0625x; 1.0625x over previous
//
#include <hip/hip_runtime.h>
#include <hip/hip_bf16.h>

// ---- types ----
typedef __bf16 bf16_t;
typedef __bf16 bf16x8 __attribute__((ext_vector_type(8)));
typedef __bf16 bf16x4 __attribute__((ext_vector_type(4)));
typedef float  f32x4  __attribute__((ext_vector_type(4)));

#define NROWS 8192
#define INDIM 256
#define HID   256
#define NCAT  512

// async global->LDS, 16B per lane (dest = wave-uniform base + lane*16)
__device__ __forceinline__ void gload16(const bf16_t* g, bf16_t* l) {
    __builtin_amdgcn_global_load_lds(
        (const __attribute__((address_space(1))) void*)g,
        (__attribute__((address_space(3))) void*)l,
        16, 0, 0);
}

// raw barrier (no implicit cnt drain)
__device__ __forceinline__ void bar() {
    asm volatile("" ::: "memory");
    __builtin_amdgcn_s_barrier();
    asm volatile("" ::: "memory");
}

#define VMCNT0 asm volatile("s_waitcnt vmcnt(0)" ::: "memory")
#define LGKM0  asm volatile("s_waitcnt lgkmcnt(0)" ::: "memory")

// ============ kernel 1: row sums (read-only) + weight transposes ============
__global__ __launch_bounds__(256) void k_rowsum(const float* __restrict__ adj,
                                                float* __restrict__ d_inv,
                                                const float* __restrict__ Wf,
                                                const float* __restrict__ Ws,
                                                bf16_t* __restrict__ Wtf,
                                                bf16_t* __restrict__ Wts) {
    const int b = blockIdx.x;
    if (b >= NROWS / 4) {
        const int i = (b - NROWS / 4) * 256 + threadIdx.x;
        const int n = i >> 8, k = i & 255;
        Wtf[i] = (bf16_t)Wf[k * 256 + n];
        Wts[i] = (bf16_t)Ws[k * 256 + n];
        return;
    }
    const int lane = threadIdx.x & 63;
    const int wid  = threadIdx.x >> 6;
    const int row  = b * 4 + wid;
    const float4* rp = (const float4*)(adj + (size_t)row * NROWS);
    float s = 0.f;
#pragma unroll 8
    for (int i = lane; i < NROWS / 4; i += 64) {
        float4 v = rp[i];
        s += (v.x + v.y) + (v.z + v.w);
    }
#pragma unroll
    for (int off = 32; off; off >>= 1) s += __shfl_down(s, off);
    if (lane == 0) d_inv[row] = 1.0f / sqrtf(s + 1e-9f);
}

// ===================== kernel 2: Yt[c][j] = bf16(d_j * X[j][c]) ==============
__global__ __launch_bounds__(256) void k_prep_x(const float* __restrict__ fx,
                                                const float* __restrict__ sx,
                                                const float* __restrict__ d_inv,
                                                bf16_t* __restrict__ Yt) {
    __shared__ bf16_t T[64][72];
    const int tid = threadIdx.x;
    const int j0 = blockIdx.x * 64;
    const int c0 = blockIdx.y * 64;
    const float* src = (c0 < 256) ? fx : sx;
    const int cc0 = (c0 < 256) ? c0 : (c0 - 256);
#pragma unroll
    for (int i = 0; i < 4; ++i) {
        int s = tid + i * 256;
        int jr = s >> 4, c4 = (s & 15) * 4;
        float dj = d_inv[j0 + jr];
        float4 v = *(const float4*)(src + (size_t)(j0 + jr) * 256 + cc0 + c4);
        bf16x4 o;
        o[0] = (bf16_t)(v.x * dj); o[1] = (bf16_t)(v.y * dj);
        o[2] = (bf16_t)(v.z * dj); o[3] = (bf16_t)(v.w * dj);
        *(bf16x4*)(&T[jr][c4]) = o;
    }
    __syncthreads();
#pragma unroll
    for (int i = 0; i < 4; ++i) {
        int s = tid + i * 256;
        int cr = s >> 4, j4 = (s & 15) * 4;
        bf16x4 o;
        o[0] = T[j4 + 0][cr]; o[1] = T[j4 + 1][cr];
        o[2] = T[j4 + 2][cr]; o[3] = T[j4 + 3][cr];
        *(bf16x4*)(Yt + (size_t)(c0 + cr) * NROWS + j0 + j4) = o;
    }
}

// ========= kernel 3: 256x256 GEMM, 4-phase/tile, compiler-certified prereads
// Round-2's verified stage distribution + counted-vmcnt chain, with each
// phase's MFMA fragments pre-read in the PREVIOUS phase and certified by the
// COMPILER's lgkmcnt placed before the first consuming MFMA -- i.e. after the
// intervening barrier (m201's pattern), with NO hand-written drains (round
// 4's LGKM0-before-bar forced every wave to drain reads+writes at every
// barrier arrival -> 9.5us regression).
// Overwrite-safety (provable, per slot): read certified (pre-MFMA lgkm)
// >= 1 barrier before that slot's overwrite is issued:
//   bB<-Bh1 read Ph1-end, certified Ph2 pre-mfma, Bh1 DMA issued Ph3.
//   af<-Ah1 read Ph2-end, certified Ph3 pre-mfma, Ah1 write issued Ph4.
//   next-tile af,bA,bB read Ph4-end, certified Ph1' pre-mfma,
//   overwrites issued Ph2'/Ph3'.
// DMA-landing certification (cross-wave): each wave's a_write_half drains its
// own older DMAs (implicit counted vmcnt on R), then a barrier precedes any
// read of the staged slot; tail covered by VMCNT0 at tt==NT-2 (placed before
// that phase's prereads of tile NT-1).

__device__ __forceinline__ void stage_b(bf16_t* dst, const bf16_t* gsrc,
                                        int tid) {
#pragma unroll
    for (int c = 0; c < 2; ++c) {
        int r    = c * 64 + (tid >> 3);
        int gcol = ((tid & 7) * 8) ^ ((r & 7) * 8);   // involution
        gload16(gsrc + (size_t)r * NROWS + gcol, dst + c * 4096 + tid * 8);
    }
}

// fp32 A half-tile (128 rows x 64 cols): 2 rows/thread, 8 f32 each -> 4 f32x4
__device__ __forceinline__ void a_load_half(const float* Ag, int h, size_t k2,
                                            int tid, f32x4 R[4]) {
#pragma unroll
    for (int c = 0; c < 2; ++c) {
        const float* p = Ag + (size_t)(h * 128 + c * 64 + (tid >> 3)) * NROWS
                            + k2 + (tid & 7) * 8;
        R[c * 2 + 0] = *(const f32x4*)(p);
        R[c * 2 + 1] = *(const f32x4*)(p + 4);
    }
}

// cvt + write with the SAME XOR swizzle the read path uses (write-side)
__device__ __forceinline__ void a_write_half(bf16_t* dst, const f32x4 R[4],
                                             int tid) {
#pragma unroll
    for (int c = 0; c < 2; ++c) {
        int r   = c * 64 + (tid >> 3);
        int col = ((tid & 7) * 8) ^ ((r & 7) * 8);
        f32x4 v0 = R[c * 2], v1 = R[c * 2 + 1];
        bf16x8 o;
        o[0] = (bf16_t)v0[0]; o[1] = (bf16_t)v0[1];
        o[2] = (bf16_t)v0[2]; o[3] = (bf16_t)v0[3];
        o[4] = (bf16_t)v1[0]; o[5] = (bf16_t)v1[1];
        o[6] = (bf16_t)v1[2]; o[7] = (bf16_t)v1[3];
        *(bf16x8*)(dst + r * 64 + col) = o;
    }
}

__device__ __forceinline__ void frag_a(const bf16_t* base, bf16x8 af[4][2],
                                       int arow, int c0, int c1) {
#pragma unroll
    for (int mi = 0; mi < 4; ++mi) {
        af[mi][0] = *(const bf16x8*)(base + (arow + mi * 16) * 64 + c0);
        af[mi][1] = *(const bf16x8*)(base + (arow + mi * 16) * 64 + c1);
    }
}

__device__ __forceinline__ void frag_b(const bf16_t* base, bf16x8 bf2[2][2],
                                       int brow, int c0, int c1) {
#pragma unroll
    for (int ni = 0; ni < 2; ++ni) {
        bf2[ni][0] = *(const bf16x8*)(base + (brow + ni * 16) * 64 + c0);
        bf2[ni][1] = *(const bf16x8*)(base + (brow + ni * 16) * 64 + c1);
    }
}

template <int Q>
__device__ __forceinline__ void mfma_q(f32x4 acc[4][4][2],
                                       const bf16x8 af[4][2],
                                       const bf16x8 bf2[2][2]) {
    __builtin_amdgcn_s_setprio(1);
#pragma unroll
    for (int ks = 0; ks < 2; ++ks)
#pragma unroll
        for (int mi = 0; mi < 4; ++mi)
#pragma unroll
            for (int ni = 0; ni < 2; ++ni)
                acc[Q][mi][ni] = __builtin_amdgcn_mfma_f32_16x16x32_bf16(
                    af[mi][ks], bf2[ni][ks], acc[Q][mi][ni], 0, 0, 0);
    __builtin_amdgcn_s_setprio(0);
}

__global__ __launch_bounds__(512, 2) void k_gemm8(const float* __restrict__ adj,
                                                  const bf16_t* __restrict__ Yt,
                                                  bf16_t* __restrict__ msgp,
                                                  int KCH) {
    __shared__ bf16_t SH[8 * 8192];              // 128 KB contiguous
    bf16_t* As = SH;                             // A half-slots 0..3
    bf16_t* Bs = SH + 4 * 8192;                  // B half-slots 0..3
    const int tid  = threadIdx.x;
    const int lane = tid & 63;
    const int w    = tid >> 6;
    const int wrow = w >> 2, wcol = w & 3;       // 2M x 4N waves
    const int lr = lane & 15, hi = lane >> 4;

    // z-per-XCD decode (round-robin dispatch assumption; perf heuristic only)
    const int bid = blockIdx.x;
    const int c  = bid & 7;                      // XCD
    const int j  = bid >> 3;                     // 0..31 within XCD
    const int z  = c >> 1;                       // K-chunk pinned to XCD pair
    const int y  = (c & 1) * 16 + (j >> 1);
    const int x  = j & 1;
    const int m0 = y * 256, n0 = x * 256;
    const size_t kbase = (size_t)z * KCH;

    const float*  Ag = adj + (size_t)m0 * NROWS + kbase;
    const bf16_t* Bg = Yt + (size_t)n0 * NROWS + kbase;

    const int sw = (lr & 7) * 8;                 // read-side swizzle
    const int c0 = (hi * 8) ^ sw;
    const int c1 = c0 ^ 32;
    const int arow = wrow * 64 + lr;
    const int brow = wcol * 32 + lr;

    f32x4 acc[4][4][2] = {};
    const int NT = KCH / 64;                     // tiles (even)

    // steady-state register state, live across tiles
    f32x4 R[4];                                  // A staging buffer (16 VGPR)
    bf16x8 af[4][2], bA[2][2], bB[2][2];         // MFMA fragments (64 VGPR)

    // prologue: B tiles 0,1 via DMA; A tiles 0,1 via reg-cvt
    {
        f32x4 T[4];
        stage_b(Bs + 0 * 8192, Bg, tid);
        stage_b(Bs + 1 * 8192, Bg + (size_t)128 * NROWS, tid);
        stage_b(Bs + 2 * 8192, Bg + 64, tid);
        stage_b(Bs + 3 * 8192, Bg + (size_t)128 * NROWS + 64, tid);
        a_load_half(Ag, 0, 0, tid, R);
        a_load_half(Ag, 1, 0, tid, T);
        a_write_half(As + 0 * 8192, R, tid);
        a_write_half(As + 1 * 8192, T, tid);
        a_load_half(Ag, 0, 64, tid, R);
        a_load_half(Ag, 1, 64, tid, T);
        a_write_half(As + 2 * 8192, R, tid);     // cvt waits k=64 loads ->
        a_write_half(As + 3 * 8192, T, tid);     //   all 4 B DMAs (older) done
        a_load_half(Ag, 0, 128, tid, R);         // R <- (t2,h0), in flight
        LGKM0;                                   // own ds_writes published
    }
    bar();                                       // ALL waves' writes visible
    // preload tile-0 Ph1 fragments (reads after the barrier: cross-wave data
    // valid; certified by compiler lgkm before the first consuming MFMA)
    frag_a(As + 0 * 8192, af, arow, c0, c1);
    frag_b(Bs + 0 * 8192, bA, brow, c0, c1);

    // per-tile body: 4 phases, one quadrant each (Q00,Q01,Q11,Q10); every
    // phase's fragments were pre-read in the previous phase.
#define TBODY(PP, tt)                                                         \
    {                                                                         \
        bf16_t* Ah0 = As + ((PP) * 2 + 0) * 8192;                             \
        bf16_t* Ah1 = As + ((PP) * 2 + 1) * 8192;                             \
        bf16_t* Bh0 = Bs + ((PP) * 2 + 0) * 8192;                             \
        bf16_t* Bh1 = Bs + ((PP) * 2 + 1) * 8192;                             \
        bf16_t* An0 = As + (((PP) ^ 1) * 2 + 0) * 8192;                       \
        bf16_t* Bn0 = Bs + (((PP) ^ 1) * 2 + 0) * 8192;                       \
        bf16_t* Bn1 = Bs + (((PP) ^ 1) * 2 + 1) * 8192;                       \
        const bool full  = ((tt) <= NT - 3);                                  \
        const bool fnext = ((tt) <= NT - 4);                                  \
        const size_t k2 = (size_t)((tt) + 2) * 64;                            \
        const size_t k3 = (size_t)((tt) + 3) * 64;                            \
        /* Ph1: af,bA preloaded.  Preload bB (no WAR: old bB dead).      */   \
        frag_b(Bh1, bB, brow, c0, c1);                                        \
        mfma_q<0>(acc, af, bA);                                               \
        bar();                                                                \
        /* Ph2: stage Bh0<-t+2; Ah0<-R (counted vmcnt: B DMAs in flight); */  \
        /*      R<-(t+2,h1).  MFMA Q01.  Preload af<-Ah1 (after use).     */  \
        if (full) {                                                           \
            stage_b(Bh0, Bg + k2, tid);                                       \
            a_write_half(Ah0, R, tid);                                        \
            a_load_half(Ag, 1, k2, tid, R);                                   \
        }                                                                     \
        mfma_q<1>(acc, af, bB);                                               \
        frag_a(Ah1, af, arow, c0, c1);                                        \
        bar();                                                                \
        /* Ph3: stage Bh1<-t+2 (bB certified one barrier ago).  MFMA Q11. */  \
        if (full) stage_b(Bh1, Bg + (size_t)128 * NROWS + k2, tid);           \
        mfma_q<3>(acc, af, bB);                                               \
        bar();                                                                \
        /* Ph4: Ah1<-R; R<-(t+3,h0); tail drain; MFMA Q10; preload next. */   \
        if (full) a_write_half(Ah1, R, tid);                                  \
        if (fnext) a_load_half(Ag, 0, k3, tid, R);                            \
        if ((tt) == NT - 2) VMCNT0;                                           \
        mfma_q<2>(acc, af, bA);                                               \
        if ((tt) != NT - 1) {                                                 \
            frag_a(An0, af, arow, c0, c1);                                    \
            frag_b(Bn0, bA, brow, c0, c1);                                    \
        }                                                                     \
        bar();                                                                \
    }

    for (int t = 0; t < NT; t += 2) {
        TBODY(0, t);
        TBODY(1, t + 1);
    }
#undef TBODY

    // epilogue: LDS-transpose each 128x128 quadrant, store bf16 coalesced
    bf16_t* mpb = msgp + (size_t)z * NROWS * NCAT;
    float* ep = (float*)SH;                      // 128 x (stride 133) fp32
    const int erow = tid >> 2, ecb = (tid & 3) * 32;
#pragma unroll
    for (int q4 = 0; q4 < 4; ++q4) {
        const int qm = q4 >> 1, qn = q4 & 1;
        bar();
#pragma unroll
        for (int mi = 0; mi < 4; ++mi)
#pragma unroll
            for (int ni = 0; ni < 2; ++ni)
#pragma unroll
                for (int r = 0; r < 4; ++r)
                    ep[(wrow * 64 + mi * 16 + hi * 4 + r) * 133
                       + wcol * 32 + ni * 16 + lr] = acc[q4][mi][ni][r];
        LGKM0;
        bar();
        bf16_t* gp = mpb + (size_t)(m0 + qm * 128 + erow) * NCAT
                         + n0 + qn * 128 + ecb;
#pragma unroll
        for (int j2 = 0; j2 < 4; ++j2) {
            f32x4 v0 = *(const f32x4*)(ep + erow * 133 + ecb + j2 * 8);
            f32x4 v1 = *(const f32x4*)(ep + erow * 133 + ecb + j2 * 8 + 4);
            bf16x8 o;
            o[0] = (bf16_t)v0[0]; o[1] = (bf16_t)v0[1];
            o[2] = (bf16_t)v0[2]; o[3] = (bf16_t)v0[3];
            o[4] = (bf16_t)v1[0]; o[5] = (bf16_t)v1[1];
            o[6] = (bf16_t)v1[2]; o[7] = (bf16_t)v1[3];
            *(bf16x8*)(gp + j2 * 8) = o;
        }
    }
}

// ===================== kernel 4: H_f/H_s + attention + blend =================
template <int NP>
__global__ __launch_bounds__(256) void k_fuse(const bf16_t* __restrict__ msg,
                                              const float* __restrict__ d_inv,
                                              const bf16_t* __restrict__ Wtf,
                                              const bf16_t* __restrict__ Wts,
                                              const float* __restrict__ bfv,
                                              const float* __restrict__ bsv,
                                              const float* __restrict__ Watt,
                                              const float* __restrict__ batt,
                                              float* __restrict__ out) {
    __shared__ bf16_t Ms[32][520];
    __shared__ float attnbuf[4][32];
    const int tid = threadIdx.x, lane = tid & 63, w = tid >> 6;
    const int r0 = blockIdx.x * 32;
    const int lr = lane & 15, lk = (lane >> 4) * 8;

#pragma unroll
    for (int i = 0; i < 8; ++i) {
        int s = tid + i * 256;              // 0..2047
        int r = s >> 6, c8 = (s & 63) * 8;
        float di = d_inv[r0 + r];
        size_t off = (size_t)(r0 + r) * NCAT + c8;
        float a8[8] = {};
#pragma unroll
        for (int p = 0; p < NP; ++p) {
            bf16x8 v = *(const bf16x8*)(msg + (size_t)p * NROWS * NCAT + off);
#pragma unroll
            for (int j = 0; j < 8; ++j) a8[j] += (float)v[j];
        }
        bf16x8 o;
#pragma unroll
        for (int j = 0; j < 8; ++j) o[j] = (bf16_t)(a8[j] * di);
        *(bf16x8*)(&Ms[r][c8]) = o;
    }
    __syncthreads();

    f32x4 accf[2][4] = {}, accs[2][4] = {};
#pragma unroll
    for (int ks = 0; ks < 8; ++ks) {
        bf16x8 af[2], as2[2];
#pragma unroll
        for (int mi = 0; mi < 2; ++mi) {
            af[mi]  = *(const bf16x8*)(&Ms[mi * 16 + lr][ks * 32 + lk]);
            as2[mi] = *(const bf16x8*)(&Ms[mi * 16 + lr][256 + ks * 32 + lk]);
        }
#pragma unroll
        for (int ni = 0; ni < 4; ++ni) {
            int col = w * 64 + ni * 16 + lr;
            bf16x8 bwf = *(const bf16x8*)(Wtf + col * 256 + ks * 32 + lk);
            bf16x8 bws = *(const bf16x8*)(Wts + col * 256 + ks * 32 + lk);
#pragma unroll
            for (int mi = 0; mi < 2; ++mi) {
                accf[mi][ni] = __builtin_amdgcn_mfma_f32_16x16x32_bf16(
                    af[mi], bwf, accf[mi][ni], 0, 0, 0);
                accs[mi][ni] = __builtin_amdgcn_mfma_f32_16x16x32_bf16(
                    as2[mi], bws, accs[mi][ni], 0, 0, 0);
            }
        }
    }

    float par[2][4] = {};
#pragma unroll
    for (int ni = 0; ni < 4; ++ni) {
        int col = w * 64 + ni * 16 + lr;
        float bf_ = bfv[col], bs_ = bsv[col];
        float wf = Watt[col], ws_ = Watt[256 + col];
#pragma unroll
        for (int mi = 0; mi < 2; ++mi)
#pragma unroll
            for (int r = 0; r < 4; ++r) {
                float f = accf[mi][ni][r] + bf_; f = f > 0.f ? f : 0.f;
                float s = accs[mi][ni][r] + bs_; s = s > 0.f ? s : 0.f;
                accf[mi][ni][r] = f; accs[mi][ni][r] = s;
                par[mi][r] += f * wf + s * ws_;
            }
    }
#pragma unroll
    for (int off = 1; off < 16; off <<= 1)
#pragma unroll
        for (int mi = 0; mi < 2; ++mi)
#pragma unroll
            for (int r = 0; r < 4; ++r)
                par[mi][r] += __shfl_xor(par[mi][r], off);
    if (lr == 0) {
#pragma unroll
        for (int mi = 0; mi < 2; ++mi)
#pragma unroll
            for (int r = 0; r < 4; ++r)
                attnbuf[w][mi * 16 + (lane >> 4) * 4 + r] = par[mi][r];
    }
    __syncthreads();

    const float ba = batt[0];
#pragma unroll
    for (int mi = 0; mi < 2; ++mi)
#pragma unroll
        for (int r = 0; r < 4; ++r) {
            int rr = mi * 16 + (lane >> 4) * 4 + r;
            float tot = attnbuf[0][rr] + attnbuf[1][rr] + attnbuf[2][rr] +
                        attnbuf[3][rr] + ba;
            float attn = 1.0f / (1.0f + expf(-tot));
#pragma unroll
            for (int ni = 0; ni < 4; ++ni) {
                int col = w * 64 + ni * 16 + lr;
                out[(size_t)(r0 + rr) * 256 + col] =
                    attn * accf[mi][ni][r] + (1.0f - attn) * accs[mi][ni][r];
            }
        }
}

// ===================== launch =====================
extern "C" void kernel_launch(void* const* d_in, const int* in_sizes, int n_in,
                              void* d_out, int out_size, void* d_ws, size_t ws_size,
                              hipStream_t stream) {
    (void)in_sizes; (void)n_in; (void)out_size; (void)ws_size;
    const float* fx   = (const float*)d_in[0];
    const float* sx   = (const float*)d_in[1];
    const float* adj  = (const float*)d_in[2];
    const float* Wf   = (const float*)d_in[3];
    const float* bfv  = (const float*)d_in[4];
    const float* Ws   = (const float*)d_in[5];
    const float* bsv  = (const float*)d_in[6];
    const float* Watt = (const float*)d_in[7];
    const float* batt = (const float*)d_in[8];
    float* out = (float*)d_out;

    char* ws = (char*)d_ws;
    float*  d_inv = (float*)(ws);                      // 32 KB
    bf16_t* Yt    = (bf16_t*)(ws + 32768);             // 8 MB   [512][8192]
    bf16_t* Wtf   = (bf16_t*)(ws + 8421376);           // 128 KB
    bf16_t* Wts   = (bf16_t*)(ws + 8552448);           // 128 KB
    bf16_t* msgp  = (bf16_t*)(ws + 8683520);           // 4 x 8 MB bf16 partials

    const int SK = 4;                                  // KCH = 2048
    k_rowsum<<<NROWS / 4 + 256, 256, 0, stream>>>(adj, d_inv, Wf, Ws, Wtf, Wts);
    k_prep_x<<<dim3(NROWS / 64, NCAT / 64), 256, 0, stream>>>(fx, sx, d_inv, Yt);
    k_gemm8<<<64 * SK, 512, 0, stream>>>(adj, Yt, msgp, NROWS / SK);
    k_fuse<4><<<NROWS / 32, 256, 0, stream>>>(msgp, d_inv, Wtf, Wts, bfv,
                                              bsv, Watt, batt, out);
}

// Round 6
// 152.561 us; speedup vs baseline: 1.0735x; 1.0103x over previous
//
#include <hip/hip_runtime.h>
#include <hip/hip_bf16.h>

// ---- types ----
typedef __bf16 bf16_t;
typedef __bf16 bf16x8 __attribute__((ext_vector_type(8)));
typedef __bf16 bf16x4 __attribute__((ext_vector_type(4)));
typedef float  f32x4  __attribute__((ext_vector_type(4)));

#define NROWS 8192
#define INDIM 256
#define HID   256
#define NCAT  512

// async global->LDS, 16B per lane (dest = wave-uniform base + lane*16)
__device__ __forceinline__ void gload16(const bf16_t* g, bf16_t* l) {
    __builtin_amdgcn_global_load_lds(
        (const __attribute__((address_space(1))) void*)g,
        (__attribute__((address_space(3))) void*)l,
        16, 0, 0);
}

// raw barrier (no implicit cnt drain)
__device__ __forceinline__ void bar() {
    asm volatile("" ::: "memory");
    __builtin_amdgcn_s_barrier();
    asm volatile("" ::: "memory");
}

#define VMCNT0 asm volatile("s_waitcnt vmcnt(0)" ::: "memory")
#define LGKM0  asm volatile("s_waitcnt lgkmcnt(0)" ::: "memory")

// ============ kernel 1: row sums (read-only) + weight transposes ============
__global__ __launch_bounds__(256) void k_rowsum(const float* __restrict__ adj,
                                                float* __restrict__ d_inv,
                                                const float* __restrict__ Wf,
                                                const float* __restrict__ Ws,
                                                bf16_t* __restrict__ Wtf,
                                                bf16_t* __restrict__ Wts) {
    const int b = blockIdx.x;
    if (b >= NROWS / 4) {
        const int i = (b - NROWS / 4) * 256 + threadIdx.x;
        const int n = i >> 8, k = i & 255;
        Wtf[i] = (bf16_t)Wf[k * 256 + n];
        Wts[i] = (bf16_t)Ws[k * 256 + n];
        return;
    }
    const int lane = threadIdx.x & 63;
    const int wid  = threadIdx.x >> 6;
    const int row  = b * 4 + wid;
    const float4* rp = (const float4*)(adj + (size_t)row * NROWS);
    float s = 0.f;
#pragma unroll 8
    for (int i = lane; i < NROWS / 4; i += 64) {
        float4 v = rp[i];
        s += (v.x + v.y) + (v.z + v.w);
    }
#pragma unroll
    for (int off = 32; off; off >>= 1) s += __shfl_down(s, off);
    if (lane == 0) d_inv[row] = 1.0f / sqrtf(s + 1e-9f);
}

// ===================== kernel 2: Yt[c][j] = bf16(d_j * X[j][c]) ==============
__global__ __launch_bounds__(256) void k_prep_x(const float* __restrict__ fx,
                                                const float* __restrict__ sx,
                                                const float* __restrict__ d_inv,
                                                bf16_t* __restrict__ Yt) {
    __shared__ bf16_t T[64][72];
    const int tid = threadIdx.x;
    const int j0 = blockIdx.x * 64;
    const int c0 = blockIdx.y * 64;
    const float* src = (c0 < 256) ? fx : sx;
    const int cc0 = (c0 < 256) ? c0 : (c0 - 256);
#pragma unroll
    for (int i = 0; i < 4; ++i) {
        int s = tid + i * 256;
        int jr = s >> 4, c4 = (s & 15) * 4;
        float dj = d_inv[j0 + jr];
        float4 v = *(const float4*)(src + (size_t)(j0 + jr) * 256 + cc0 + c4);
        bf16x4 o;
        o[0] = (bf16_t)(v.x * dj); o[1] = (bf16_t)(v.y * dj);
        o[2] = (bf16_t)(v.z * dj); o[3] = (bf16_t)(v.w * dj);
        *(bf16x4*)(&T[jr][c4]) = o;
    }
    __syncthreads();
#pragma unroll
    for (int i = 0; i < 4; ++i) {
        int s = tid + i * 256;
        int cr = s >> 4, j4 = (s & 15) * 4;
        bf16x4 o;
        o[0] = T[j4 + 0][cr]; o[1] = T[j4 + 1][cr];
        o[2] = T[j4 + 2][cr]; o[3] = T[j4 + 3][cr];
        *(bf16x4*)(Yt + (size_t)(c0 + cr) * NROWS + j0 + j4) = o;
    }
}

// ========= kernel 3: 256x256 GEMM, 4-phase/tile, MFMA-FIRST phases =========
// Identical producer/consumer schedule to round 5 (which passed), with ONE
// order change: the MFMA cluster opens each phase; staging (stage_b DMA,
// a_write_half with its compiler-inserted counted vmcnt wait on R, a_load)
// and next-phase prereads FOLLOW it.  Rationale: s_setprio is a scheduling
// fence, so source order is emitted order -- previous rounds made every wave
// serialize the a_write vmcnt wait (HBM-latency-exposed) BEFORE its MFMAs in
// every other phase, inside the 8-wave barrier convoy.  Now that wait
// overlaps SIMD-mate MFMA issue.
// Safety distances unchanged (re-audited):
//   - every preread certified (compiler lgkm before first consuming MFMA,
//     after the barrier) >= 1 barrier before its slot's overwrite issues;
//   - writer's FIFO lgkm drain before its next MFMA publishes ds_writes
//     >= 2 barriers before any cross-wave read;
//   - VMCNT0 at tt==NT-2 moved after the MFMA but before the dependent
//     prereads of tile NT-1.

__device__ __forceinline__ void stage_b(bf16_t* dst, const bf16_t* gsrc,
                                        int tid) {
#pragma unroll
    for (int c = 0; c < 2; ++c) {
        int r    = c * 64 + (tid >> 3);
        int gcol = ((tid & 7) * 8) ^ ((r & 7) * 8);   // involution
        gload16(gsrc + (size_t)r * NROWS + gcol, dst + c * 4096 + tid * 8);
    }
}

// fp32 A half-tile (128 rows x 64 cols): 2 rows/thread, 8 f32 each -> 4 f32x4
__device__ __forceinline__ void a_load_half(const float* Ag, int h, size_t k2,
                                            int tid, f32x4 R[4]) {
#pragma unroll
    for (int c = 0; c < 2; ++c) {
        const float* p = Ag + (size_t)(h * 128 + c * 64 + (tid >> 3)) * NROWS
                            + k2 + (tid & 7) * 8;
        R[c * 2 + 0] = *(const f32x4*)(p);
        R[c * 2 + 1] = *(const f32x4*)(p + 4);
    }
}

// cvt + write with the SAME XOR swizzle the read path uses (write-side)
__device__ __forceinline__ void a_write_half(bf16_t* dst, const f32x4 R[4],
                                             int tid) {
#pragma unroll
    for (int c = 0; c < 2; ++c) {
        int r   = c * 64 + (tid >> 3);
        int col = ((tid & 7) * 8) ^ ((r & 7) * 8);
        f32x4 v0 = R[c * 2], v1 = R[c * 2 + 1];
        bf16x8 o;
        o[0] = (bf16_t)v0[0]; o[1] = (bf16_t)v0[1];
        o[2] = (bf16_t)v0[2]; o[3] = (bf16_t)v0[3];
        o[4] = (bf16_t)v1[0]; o[5] = (bf16_t)v1[1];
        o[6] = (bf16_t)v1[2]; o[7] = (bf16_t)v1[3];
        *(bf16x8*)(dst + r * 64 + col) = o;
    }
}

__device__ __forceinline__ void frag_a(const bf16_t* base, bf16x8 af[4][2],
                                       int arow, int c0, int c1) {
#pragma unroll
    for (int mi = 0; mi < 4; ++mi) {
        af[mi][0] = *(const bf16x8*)(base + (arow + mi * 16) * 64 + c0);
        af[mi][1] = *(const bf16x8*)(base + (arow + mi * 16) * 64 + c1);
    }
}

__device__ __forceinline__ void frag_b(const bf16_t* base, bf16x8 bf2[2][2],
                                       int brow, int c0, int c1) {
#pragma unroll
    for (int ni = 0; ni < 2; ++ni) {
        bf2[ni][0] = *(const bf16x8*)(base + (brow + ni * 16) * 64 + c0);
        bf2[ni][1] = *(const bf16x8*)(base + (brow + ni * 16) * 64 + c1);
    }
}

template <int Q>
__device__ __forceinline__ void mfma_q(f32x4 acc[4][4][2],
                                       const bf16x8 af[4][2],
                                       const bf16x8 bf2[2][2]) {
    __builtin_amdgcn_s_setprio(1);
#pragma unroll
    for (int ks = 0; ks < 2; ++ks)
#pragma unroll
        for (int mi = 0; mi < 4; ++mi)
#pragma unroll
            for (int ni = 0; ni < 2; ++ni)
                acc[Q][mi][ni] = __builtin_amdgcn_mfma_f32_16x16x32_bf16(
                    af[mi][ks], bf2[ni][ks], acc[Q][mi][ni], 0, 0, 0);
    __builtin_amdgcn_s_setprio(0);
}

__global__ __launch_bounds__(512, 2) void k_gemm8(const float* __restrict__ adj,
                                                  const bf16_t* __restrict__ Yt,
                                                  bf16_t* __restrict__ msgp,
                                                  int KCH) {
    __shared__ bf16_t SH[8 * 8192];              // 128 KB contiguous
    bf16_t* As = SH;                             // A half-slots 0..3
    bf16_t* Bs = SH + 4 * 8192;                  // B half-slots 0..3
    const int tid  = threadIdx.x;
    const int lane = tid & 63;
    const int w    = tid >> 6;
    const int wrow = w >> 2, wcol = w & 3;       // 2M x 4N waves
    const int lr = lane & 15, hi = lane >> 4;

    // z-per-XCD decode (round-robin dispatch assumption; perf heuristic only)
    const int bid = blockIdx.x;
    const int c  = bid & 7;                      // XCD
    const int j  = bid >> 3;                     // 0..31 within XCD
    const int z  = c >> 1;                       // K-chunk pinned to XCD pair
    const int y  = (c & 1) * 16 + (j >> 1);
    const int x  = j & 1;
    const int m0 = y * 256, n0 = x * 256;
    const size_t kbase = (size_t)z * KCH;

    const float*  Ag = adj + (size_t)m0 * NROWS + kbase;
    const bf16_t* Bg = Yt + (size_t)n0 * NROWS + kbase;

    const int sw = (lr & 7) * 8;                 // read-side swizzle
    const int c0 = (hi * 8) ^ sw;
    const int c1 = c0 ^ 32;
    const int arow = wrow * 64 + lr;
    const int brow = wcol * 32 + lr;

    f32x4 acc[4][4][2] = {};
    const int NT = KCH / 64;                     // tiles (even)

    // steady-state register state, live across tiles
    f32x4 R[4];                                  // A staging buffer (16 VGPR)
    bf16x8 af[4][2], bA[2][2], bB[2][2];         // MFMA fragments (64 VGPR)

    // prologue: B tiles 0,1 via DMA; A tiles 0,1 via reg-cvt
    {
        f32x4 T[4];
        stage_b(Bs + 0 * 8192, Bg, tid);
        stage_b(Bs + 1 * 8192, Bg + (size_t)128 * NROWS, tid);
        stage_b(Bs + 2 * 8192, Bg + 64, tid);
        stage_b(Bs + 3 * 8192, Bg + (size_t)128 * NROWS + 64, tid);
        a_load_half(Ag, 0, 0, tid, R);
        a_load_half(Ag, 1, 0, tid, T);
        a_write_half(As + 0 * 8192, R, tid);
        a_write_half(As + 1 * 8192, T, tid);
        a_load_half(Ag, 0, 64, tid, R);
        a_load_half(Ag, 1, 64, tid, T);
        a_write_half(As + 2 * 8192, R, tid);     // cvt waits k=64 loads ->
        a_write_half(As + 3 * 8192, T, tid);     //   all 4 B DMAs (older) done
        a_load_half(Ag, 0, 128, tid, R);         // R <- (t2,h0), in flight
        LGKM0;                                   // own ds_writes published
    }
    bar();                                       // ALL waves' writes visible
    // preload tile-0 Ph1 fragments (reads after the barrier: cross-wave data
    // valid; certified by compiler lgkm before the first consuming MFMA)
    frag_a(As + 0 * 8192, af, arow, c0, c1);
    frag_b(Bs + 0 * 8192, bA, brow, c0, c1);

    // per-tile body: 4 phases, one quadrant each (Q00,Q01,Q11,Q10), MFMA at
    // the TOP of every phase; staging + prereads after.
#define TBODY(PP, tt)                                                         \
    {                                                                         \
        bf16_t* Ah0 = As + ((PP) * 2 + 0) * 8192;                             \
        bf16_t* Ah1 = As + ((PP) * 2 + 1) * 8192;                             \
        bf16_t* Bh0 = Bs + ((PP) * 2 + 0) * 8192;                             \
        bf16_t* Bh1 = Bs + ((PP) * 2 + 1) * 8192;                             \
        bf16_t* An0 = As + (((PP) ^ 1) * 2 + 0) * 8192;                       \
        bf16_t* Bn0 = Bs + (((PP) ^ 1) * 2 + 0) * 8192;                       \
        const bool full  = ((tt) <= NT - 3);                                  \
        const bool fnext = ((tt) <= NT - 4);                                  \
        const size_t k2 = (size_t)((tt) + 2) * 64;                            \
        const size_t k3 = (size_t)((tt) + 3) * 64;                            \
        /* Ph1: MFMA Q00 (af,bA preloaded); then preread bB (old bB dead). */ \
        mfma_q<0>(acc, af, bA);                                               \
        frag_b(Bh1, bB, brow, c0, c1);                                        \
        bar();                                                                \
        /* Ph2: MFMA Q01; then stage Bh0<-t+2, Ah0<-R (counted vmcnt),    */  \
        /*      R<-(t+2,h1); preread af<-Ah1 last (latency crosses bar).  */  \
        mfma_q<1>(acc, af, bB);                                               \
        if (full) {                                                           \
            stage_b(Bh0, Bg + k2, tid);                                       \
            a_write_half(Ah0, R, tid);                                        \
            a_load_half(Ag, 1, k2, tid, R);                                   \
        }                                                                     \
        frag_a(Ah1, af, arow, c0, c1);                                        \
        bar();                                                                \
        /* Ph3: MFMA Q11; then stage Bh1<-t+2 (bB certified in Ph2). */       \
        mfma_q<3>(acc, af, bB);                                               \
        if (full) stage_b(Bh1, Bg + (size_t)128 * NROWS + k2, tid);           \
        bar();                                                                \
        /* Ph4: MFMA Q10; then Ah1<-R, R<-(t+3,h0), tail drain, prereads. */  \
        mfma_q<2>(acc, af, bA);                                               \
        if (full) a_write_half(Ah1, R, tid);                                  \
        if (fnext) a_load_half(Ag, 0, k3, tid, R);                            \
        if ((tt) == NT - 2) VMCNT0;                                           \
        if ((tt) != NT - 1) {                                                 \
            frag_a(An0, af, arow, c0, c1);                                    \
            frag_b(Bn0, bA, brow, c0, c1);                                    \
        }                                                                     \
        bar();                                                                \
    }

    for (int t = 0; t < NT; t += 2) {
        TBODY(0, t);
        TBODY(1, t + 1);
    }
#undef TBODY

    // epilogue: LDS-transpose each 128x128 quadrant, store bf16 coalesced
    bf16_t* mpb = msgp + (size_t)z * NROWS * NCAT;
    float* ep = (float*)SH;                      // 128 x (stride 133) fp32
    const int erow = tid >> 2, ecb = (tid & 3) * 32;
#pragma unroll
    for (int q4 = 0; q4 < 4; ++q4) {
        const int qm = q4 >> 1, qn = q4 & 1;
        bar();
#pragma unroll
        for (int mi = 0; mi < 4; ++mi)
#pragma unroll
            for (int ni = 0; ni < 2; ++ni)
#pragma unroll
                for (int r = 0; r < 4; ++r)
                    ep[(wrow * 64 + mi * 16 + hi * 4 + r) * 133
                       + wcol * 32 + ni * 16 + lr] = acc[q4][mi][ni][r];
        LGKM0;
        bar();
        bf16_t* gp = mpb + (size_t)(m0 + qm * 128 + erow) * NCAT
                         + n0 + qn * 128 + ecb;
#pragma unroll
        for (int j2 = 0; j2 < 4; ++j2) {
            f32x4 v0 = *(const f32x4*)(ep + erow * 133 + ecb + j2 * 8);
            f32x4 v1 = *(const f32x4*)(ep + erow * 133 + ecb + j2 * 8 + 4);
            bf16x8 o;
            o[0] = (bf16_t)v0[0]; o[1] = (bf16_t)v0[1];
            o[2] = (bf16_t)v0[2]; o[3] = (bf16_t)v0[3];
            o[4] = (bf16_t)v1[0]; o[5] = (bf16_t)v1[1];
            o[6] = (bf16_t)v1[2]; o[7] = (bf16_t)v1[3];
            *(bf16x8*)(gp + j2 * 8) = o;
        }
    }
}

// ===================== kernel 4: H_f/H_s + attention + blend =================
template <int NP>
__global__ __launch_bounds__(256) void k_fuse(const bf16_t* __restrict__ msg,
                                              const float* __restrict__ d_inv,
                                              const bf16_t* __restrict__ Wtf,
                                              const bf16_t* __restrict__ Wts,
                                              const float* __restrict__ bfv,
                                              const float* __restrict__ bsv,
                                              const float* __restrict__ Watt,
                                              const float* __restrict__ batt,
                                              float* __restrict__ out) {
    __shared__ bf16_t Ms[32][520];
    __shared__ float attnbuf[4][32];
    const int tid = threadIdx.x, lane = tid & 63, w = tid >> 6;
    const int r0 = blockIdx.x * 32;
    const int lr = lane & 15, lk = (lane >> 4) * 8;

#pragma unroll
    for (int i = 0; i < 8; ++i) {
        int s = tid + i * 256;              // 0..2047
        int r = s >> 6, c8 = (s & 63) * 8;
        float di = d_inv[r0 + r];
        size_t off = (size_t)(r0 + r) * NCAT + c8;
        float a8[8] = {};
#pragma unroll
        for (int p = 0; p < NP; ++p) {
            bf16x8 v = *(const bf16x8*)(msg + (size_t)p * NROWS * NCAT + off);
#pragma unroll
            for (int j = 0; j < 8; ++j) a8[j] += (float)v[j];
        }
        bf16x8 o;
#pragma unroll
        for (int j = 0; j < 8; ++j) o[j] = (bf16_t)(a8[j] * di);
        *(bf16x8*)(&Ms[r][c8]) = o;
    }
    __syncthreads();

    f32x4 accf[2][4] = {}, accs[2][4] = {};
#pragma unroll
    for (int ks = 0; ks < 8; ++ks) {
        bf16x8 af[2], as2[2];
#pragma unroll
        for (int mi = 0; mi < 2; ++mi) {
            af[mi]  = *(const bf16x8*)(&Ms[mi * 16 + lr][ks * 32 + lk]);
            as2[mi] = *(const bf16x8*)(&Ms[mi * 16 + lr][256 + ks * 32 + lk]);
        }
#pragma unroll
        for (int ni = 0; ni < 4; ++ni) {
            int col = w * 64 + ni * 16 + lr;
            bf16x8 bwf = *(const bf16x8*)(Wtf + col * 256 + ks * 32 + lk);
            bf16x8 bws = *(const bf16x8*)(Wts + col * 256 + ks * 32 + lk);
#pragma unroll
            for (int mi = 0; mi < 2; ++mi) {
                accf[mi][ni] = __builtin_amdgcn_mfma_f32_16x16x32_bf16(
                    af[mi], bwf, accf[mi][ni], 0, 0, 0);
                accs[mi][ni] = __builtin_amdgcn_mfma_f32_16x16x32_bf16(
                    as2[mi], bws, accs[mi][ni], 0, 0, 0);
            }
        }
    }

    float par[2][4] = {};
#pragma unroll
    for (int ni = 0; ni < 4; ++ni) {
        int col = w * 64 + ni * 16 + lr;
        float bf_ = bfv[col], bs_ = bsv[col];
        float wf = Watt[col], ws_ = Watt[256 + col];
#pragma unroll
        for (int mi = 0; mi < 2; ++mi)
#pragma unroll
            for (int r = 0; r < 4; ++r) {
                float f = accf[mi][ni][r] + bf_; f = f > 0.f ? f : 0.f;
                float s = accs[mi][ni][r] + bs_; s = s > 0.f ? s : 0.f;
                accf[mi][ni][r] = f; accs[mi][ni][r] = s;
                par[mi][r] += f * wf + s * ws_;
            }
    }
#pragma unroll
    for (int off = 1; off < 16; off <<= 1)
#pragma unroll
        for (int mi = 0; mi < 2; ++mi)
#pragma unroll
            for (int r = 0; r < 4; ++r)
                par[mi][r] += __shfl_xor(par[mi][r], off);
    if (lr == 0) {
#pragma unroll
        for (int mi = 0; mi < 2; ++mi)
#pragma unroll
            for (int r = 0; r < 4; ++r)
                attnbuf[w][mi * 16 + (lane >> 4) * 4 + r] = par[mi][r];
    }
    __syncthreads();

    const float ba = batt[0];
#pragma unroll
    for (int mi = 0; mi < 2; ++mi)
#pragma unroll
        for (int r = 0; r < 4; ++r) {
            int rr = mi * 16 + (lane >> 4) * 4 + r;
            float tot = attnbuf[0][rr] + attnbuf[1][rr] + attnbuf[2][rr] +
                        attnbuf[3][rr] + ba;
            float attn = 1.0f / (1.0f + expf(-tot));
#pragma unroll
            for (int ni = 0; ni < 4; ++ni) {
                int col = w * 64 + ni * 16 + lr;
                out[(size_t)(r0 + rr) * 256 + col] =
                    attn * accf[mi][ni][r] + (1.0f - attn) * accs[mi][ni][r];
            }
        }
}

// ===================== launch =====================
extern "C" void kernel_launch(void* const* d_in, const int* in_sizes, int n_in,
                              void* d_out, int out_size, void* d_ws, size_t ws_size,
                              hipStream_t stream) {
    (void)in_sizes; (void)n_in; (void)out_size; (void)ws_size;
    const float* fx   = (const float*)d_in[0];
    const float* sx   = (const float*)d_in[1];
    const float* adj  = (const float*)d_in[2];
    const float* Wf   = (const float*)d_in[3];
    const float* bfv  = (const float*)d_in[4];
    const float* Ws   = (const float*)d_in[5];
    const float* bsv  = (const float*)d_in[6];
    const float* Watt = (const float*)d_in[7];
    const float* batt = (const float*)d_in[8];
    float* out = (float*)d_out;

    char* ws = (char*)d_ws;
    float*  d_inv = (float*)(ws);                      // 32 KB
    bf16_t* Yt    = (bf16_t*)(ws + 32768);             // 8 MB   [512][8192]
    bf16_t* Wtf   = (bf16_t*)(ws + 8421376);           // 128 KB
    bf16_t* Wts   = (bf16_t*)(ws + 8552448);           // 128 KB
    bf16_t* msgp  = (bf16_t*)(ws + 8683520);           // 4 x 8 MB bf16 partials

    const int SK = 4;                                  // KCH = 2048
    k_rowsum<<<NROWS / 4 + 256, 256, 0, stream>>>(adj, d_inv, Wf, Ws, Wtf, Wts);
    k_prep_x<<<dim3(NROWS / 64, NCAT / 64), 256, 0, stream>>>(fx, sx, d_inv, Yt);
    k_gemm8<<<64 * SK, 512, 0, stream>>>(adj, Yt, msgp, NROWS / SK);
    k_fuse<4><<<NROWS / 32, 256, 0, stream>>>(msgp, d_inv, Wtf, Wts, bfv,
                                              bsv, Watt, batt, out);
}